// Round 8
// baseline (1106.424 us; speedup 1.0000x reference)
//
#include <hip/hip_runtime.h>

#define D 128
#define CLS 3
#define LAY 3
#define NBKT 8

typedef __attribute__((ext_vector_type(4))) unsigned short evus4;
typedef __attribute__((ext_vector_type(4))) float evf4;

// ---------------- CSR build ----------------
__global__ void k_count(const int* __restrict__ col, int* __restrict__ cnt, int E) {
  int e = blockIdx.x * blockDim.x + threadIdx.x;
  if (e < E) atomicAdd(&cnt[col[e]], 1);
}

// exclusive scan of PADDED counts: pad(cnt) = (cnt+15)&~15  -> rptr2
__global__ __launch_bounds__(1024) void k_exscan(const int* __restrict__ cnt,
                                                 int* __restrict__ ptr, int n) {
  __shared__ int wsum[16];
  __shared__ int s_carry;
  const int tid = threadIdx.x;
  const int lane = tid & 63, wid = tid >> 6;
  if (tid == 0) s_carry = 0;
  __syncthreads();
  for (int base = 0; base < n; base += 1024) {
    int i = base + tid;
    int v = (i < n) ? ((cnt[i] + 15) & ~15) : 0;
    int s = v;
#pragma unroll
    for (int off = 1; off < 64; off <<= 1) {
      int t = __shfl_up(s, off, 64);
      if (lane >= off) s += t;
    }
    if (lane == 63) wsum[wid] = s;
    __syncthreads();
    if (wid == 0 && lane < 16) {
      int ws = wsum[lane];
#pragma unroll
      for (int off = 1; off < 16; off <<= 1) {
        int t = __shfl_up(ws, off, 16);
        if (lane >= off) ws += t;
      }
      wsum[lane] = ws;
    }
    __syncthreads();
    int carry = s_carry;
    int woff = wid ? wsum[wid - 1] : 0;
    if (i < n) ptr[i] = carry + woff + (s - v);
    __syncthreads();
    if (tid == 1023) s_carry = carry + wsum[15];
    __syncthreads();
  }
  if (tid == 0) ptr[n] = s_carry;
}

// dinv + fill CSR padding slots with sentinel N
__global__ void k_prep(const int* __restrict__ cnt, const int* __restrict__ rptr2,
                       float* __restrict__ dinv, unsigned short* __restrict__ srcs, int N) {
  int i = blockIdx.x * blockDim.x + threadIdx.x;
  if (i < N) {
    dinv[i] = rsqrtf((float)(cnt[i] + 1));
    int e = rptr2[i] + cnt[i], e1 = rptr2[i + 1];
    for (; e < e1; ++e) srcs[e] = (unsigned short)N;  // sentinel -> zero row
  }
}

// phase A: bin edges into 8 even col-range buckets (fixed-stride pairs layout)
__global__ __launch_bounds__(256) void k_bin(const int* __restrict__ row,
                                             const int* __restrict__ col,
                                             int* __restrict__ bfill,
                                             unsigned* __restrict__ pairs,
                                             int E, float bscale, int bshift) {
  __shared__ int lh[NBKT], gbase[NBKT], lcur[NBKT];
  const int tid = threadIdx.x;
  const int chunk = (E + gridDim.x - 1) / gridDim.x;
  const int s0 = blockIdx.x * chunk;
  const int s1 = min(s0 + chunk, E);
  if (tid < NBKT) lh[tid] = 0;
  __syncthreads();
  for (int e = s0 + tid; e < s1; e += 256) {
    int b = min(NBKT - 1, (int)((float)col[e] * bscale));
    atomicAdd(&lh[b], 1);
  }
  __syncthreads();
  if (tid < NBKT) {
    gbase[tid] = atomicAdd(&bfill[tid], lh[tid]);
    lcur[tid] = 0;
  }
  __syncthreads();
  for (int e = s0 + tid; e < s1; e += 256) {
    int c = col[e], r = row[e];
    int b = min(NBKT - 1, (int)((float)c * bscale));
    int off = atomicAdd(&lcur[b], 1);
    pairs[(b << bshift) + gbase[b] + off] = ((unsigned)r << 16) | (unsigned)c;
  }
}

// phase B: XCD-affine scatter into padded CSR (bucket b only on blocks with blockIdx&7==b)
__global__ __launch_bounds__(256) void k_fill2(const unsigned* __restrict__ pairs,
                                               const int* __restrict__ bfill,
                                               const int* __restrict__ rptr2,
                                               int* __restrict__ fillc,
                                               unsigned short* __restrict__ srcs,
                                               int bshift) {
  const int b = blockIdx.x & 7;
  const int bi = blockIdx.x >> 3;
  const int cap = bfill[b];
  const int stride = (gridDim.x >> 3) * blockDim.x;
  const unsigned* __restrict__ bp = pairs + ((size_t)b << bshift);
  for (int idx = bi * blockDim.x + threadIdx.x; idx < cap; idx += stride) {
    unsigned p = bp[idx];
    int c = (int)(p & 0xFFFFu);
    int pos = rptr2[c] + atomicAdd(&fillc[c], 1);
    srcs[pos] = (unsigned short)(p >> 16);
  }
}

// zero the 8 sentinel rows of each of the 3 slice tables
__global__ void k_zsent(float* __restrict__ Tall, int N) {
  int t = blockIdx.x * blockDim.x + threadIdx.x;   // 3*8*16 = 384
  if (t < CLS * 8 * 16) {
    int c = t / 128, rem = t % 128;
    int s = rem / 16, f = rem % 16;
    Tall[((size_t)c * 8 + s) * (size_t)(N + 1) * 16 + (size_t)N * 16 + f] = 0.f;
  }
}

// ---- T0 = x * dinv, slice-major [8][N+1][16] ----
__global__ __launch_bounds__(256) void k_scale(const float* __restrict__ x,
                                               const float* __restrict__ dinv,
                                               float* __restrict__ T, int N) {
  const int s = blockIdx.y;
  const int i = blockIdx.x * 64 + (threadIdx.x >> 2);
  const int f = threadIdx.x & 3;
  if (i < N) {
    float4 v = *(const float4*)&x[(size_t)i * 128 + s * 16 + f * 4];
    float d = dinv[i];
    v.x *= d; v.y *= d; v.z *= d; v.w *= d;
    *(float4*)&T[((size_t)s * (N + 1) + i) * 16 + f * 4] = v;
  }
}

// ---- XCD-sliced gather: Z[i] = dinv[i]*(T[i] + sum T[srcs]) ----
// srcs loads + Z stores nontemporal: keep the 3.2 MB table slice L2-resident.
__global__ __launch_bounds__(256, 4) void k_gather(const float* __restrict__ T,
                                                   const int* __restrict__ rptr2,
                                                   const unsigned short* __restrict__ srcs,
                                                   const float* __restrict__ dinv,
                                                   float* __restrict__ Z, int N) {
  const int s = blockIdx.x & 7;
  const int chunk = blockIdx.x >> 3;
  const int i = chunk * 64 + (threadIdx.x >> 2);
  const int f = threadIdx.x & 3;
  if (i >= N) return;
  const float4* __restrict__ Ts = (const float4*)(T + (size_t)s * (N + 1) * 16);
  const int e0 = rptr2[i], e1 = rptr2[i + 1];
  float4 a0 = Ts[(size_t)i * 4 + f];  // self term
  float4 a1 = make_float4(0.f, 0.f, 0.f, 0.f);
  float4 a2 = make_float4(0.f, 0.f, 0.f, 0.f);
  float4 a3 = make_float4(0.f, 0.f, 0.f, 0.f);
  evus4 q = (evus4)0;
  if (e0 < e1) q = __builtin_nontemporal_load((const evus4*)(srcs + e0 + (f << 2)));
  for (int eb = e0; eb < e1; eb += 16) {
    evus4 qn = q;
    if (eb + 16 < e1) qn = __builtin_nontemporal_load((const evus4*)(srcs + eb + 16 + (f << 2)));
    const int qx = q.x, qy = q.y, qz = q.z, qw = q.w;
    float4 v[16];
#pragma unroll
    for (int k = 0; k < 16; ++k) {
      const int comp = k & 3;
      const int val = comp == 0 ? qx : comp == 1 ? qy : comp == 2 ? qz : qw;
      const int j = __shfl(val, k >> 2, 4);
      v[k] = Ts[(size_t)j * 4 + f];
    }
#pragma unroll
    for (int k = 0; k < 16; k += 4) {
      a0.x += v[k].x;     a0.y += v[k].y;     a0.z += v[k].z;     a0.w += v[k].w;
      a1.x += v[k + 1].x; a1.y += v[k + 1].y; a1.z += v[k + 1].z; a1.w += v[k + 1].w;
      a2.x += v[k + 2].x; a2.y += v[k + 2].y; a2.z += v[k + 2].z; a2.w += v[k + 2].w;
      a3.x += v[k + 3].x; a3.y += v[k + 3].y; a3.z += v[k + 3].z; a3.w += v[k + 3].w;
    }
    q = qn;
  }
  const float d = dinv[i];
  evf4 r;
  r.x = (a0.x + a1.x + a2.x + a3.x) * d;
  r.y = (a0.y + a1.y + a2.y + a3.y) * d;
  r.z = (a0.z + a1.z + a2.z + a3.z) * d;
  r.w = (a0.w + a1.w + a2.w + a3.w) * d;
  __builtin_nontemporal_store(r, (evf4*)&Z[(size_t)i * 128 + s * 16 + f * 4]);
}

// ---- batched 3-class GEMM + bias + L2-norm + ReLU (+dinv, slice-major) ----
// 128x128 tile, BK=16, 8x8 micro-tile split 4+4 rows at distance 64 (bank-conflict-free
// A reads), red[] aliased over As/Ws (16.4 KB LDS), register prefetch of next K-tile.
template <int MODE>
__global__ __launch_bounds__(256, 4) void k_gemm3(const float* __restrict__ Abase, long astride,
                                                  const float* __restrict__ Wl,
                                                  const float* __restrict__ bl,
                                                  const float* __restrict__ dinv,
                                                  float* __restrict__ Obase, long ostride,
                                                  int N) {
  __shared__ __align__(16) char smem_raw[16 * 128 * 4 * 2];  // 16 KB
  float* __restrict__ Asf = (float*)smem_raw;                // [16][128]
  float* __restrict__ Wsf = (float*)(smem_raw + 8192);       // [16][128]
  typedef float redrow[17];
  redrow* red = (redrow*)smem_raw;                           // [128][17], epilogue only

  const int c = blockIdx.y;
  const float* __restrict__ A = Abase + (size_t)c * astride;
  const float* __restrict__ W = Wl + (size_t)c * (LAY * D * D);
  const float* __restrict__ bias = bl + (size_t)c * (LAY * D);
  float* __restrict__ Out = Obase + (size_t)c * ostride;

  const int tid = threadIdx.x;
  const int tr = tid & 15;
  const int tc = tid >> 4;
  const int m0 = blockIdx.x * 128;
  float acc[8][8];
#pragma unroll
  for (int i = 0; i < 8; ++i)
#pragma unroll
    for (int j = 0; j < 8; ++j) acc[i][j] = 0.f;

  const int lr = tid >> 1;       // 0..127 A row in tile
  const int lq = tid & 1;        // k half
  const int kr0 = tid >> 5;      // W stage row (it=0)
  const int cq = tid & 31;       // W stage col quad
  const int gr_l = m0 + lr;

  // prefetch kc=0
  float4 va0 = make_float4(0.f, 0.f, 0.f, 0.f), va1 = va0;
  if (gr_l < N) {
    va0 = *(const float4*)&A[(size_t)gr_l * 128 + lq * 8];
    va1 = *(const float4*)&A[(size_t)gr_l * 128 + lq * 8 + 4];
  }
  float4 pw0 = *(const float4*)&W[(size_t)kr0 * 128 + cq * 4];
  float4 pw1 = *(const float4*)&W[(size_t)(8 + kr0) * 128 + cq * 4];

  for (int kc = 0; kc < 128; kc += 16) {
    Asf[(lq * 8 + 0) * 128 + lr] = va0.x;
    Asf[(lq * 8 + 1) * 128 + lr] = va0.y;
    Asf[(lq * 8 + 2) * 128 + lr] = va0.z;
    Asf[(lq * 8 + 3) * 128 + lr] = va0.w;
    Asf[(lq * 8 + 4) * 128 + lr] = va1.x;
    Asf[(lq * 8 + 5) * 128 + lr] = va1.y;
    Asf[(lq * 8 + 6) * 128 + lr] = va1.z;
    Asf[(lq * 8 + 7) * 128 + lr] = va1.w;
    *(float4*)&Wsf[kr0 * 128 + cq * 4] = pw0;
    *(float4*)&Wsf[(8 + kr0) * 128 + cq * 4] = pw1;
    __syncthreads();
    if (kc < 112) {  // prefetch next K-tile during compute
      const int kn = kc + 16;
      if (gr_l < N) {
        va0 = *(const float4*)&A[(size_t)gr_l * 128 + kn + lq * 8];
        va1 = *(const float4*)&A[(size_t)gr_l * 128 + kn + lq * 8 + 4];
      }
      pw0 = *(const float4*)&W[(size_t)(kn + kr0) * 128 + cq * 4];
      pw1 = *(const float4*)&W[(size_t)(kn + 8 + kr0) * 128 + cq * 4];
    }
#pragma unroll
    for (int kk = 0; kk < 16; ++kk) {
      float4 a4 = *(const float4*)&Asf[kk * 128 + tr * 4];
      float4 a4b = *(const float4*)&Asf[kk * 128 + 64 + tr * 4];
      float4 b4 = *(const float4*)&Wsf[kk * 128 + tc * 8];
      float4 b4b = *(const float4*)&Wsf[kk * 128 + tc * 8 + 4];
      float a[8] = {a4.x, a4.y, a4.z, a4.w, a4b.x, a4b.y, a4b.z, a4b.w};
      float b[8] = {b4.x, b4.y, b4.z, b4.w, b4b.x, b4b.y, b4b.z, b4b.w};
#pragma unroll
      for (int i = 0; i < 8; ++i)
#pragma unroll
        for (int j = 0; j < 8; ++j) acc[i][j] = fmaf(a[i], b[j], acc[i][j]);
    }
    __syncthreads();
  }

  // epilogue: bias, row L2-norm, relu, (dinv), store. rows: tr*4+i and 64+tr*4+i.
  const int c0 = tc * 8;
  float bj[8];
#pragma unroll
  for (int j = 0; j < 8; ++j) bj[j] = bias[c0 + j];
#pragma unroll
  for (int i = 0; i < 8; ++i) {
    const int r = (i < 4) ? (tr * 4 + i) : (64 + tr * 4 + i - 4);
    float rs = 0.f;
#pragma unroll
    for (int j = 0; j < 8; ++j) {
      acc[i][j] += bj[j];
      rs = fmaf(acc[i][j], acc[i][j], rs);
    }
    red[r][tc] = rs;
  }
  __syncthreads();
#pragma unroll
  for (int i = 0; i < 8; ++i) {
    const int r = (i < 4) ? (tr * 4 + i) : (64 + tr * 4 + i - 4);
    const int gr = m0 + r;
    if (gr >= N) continue;
    float rsum = 0.f;
#pragma unroll
    for (int q = 0; q < 16; ++q) rsum += red[r][q];
    float sc = 1.0f / fmaxf(sqrtf(rsum), 1e-12f);
    if (MODE == 0) sc *= dinv[gr];
    float4 o0, o1;
    o0.x = fmaxf(acc[i][0] * sc, 0.f);
    o0.y = fmaxf(acc[i][1] * sc, 0.f);
    o0.z = fmaxf(acc[i][2] * sc, 0.f);
    o0.w = fmaxf(acc[i][3] * sc, 0.f);
    o1.x = fmaxf(acc[i][4] * sc, 0.f);
    o1.y = fmaxf(acc[i][5] * sc, 0.f);
    o1.z = fmaxf(acc[i][6] * sc, 0.f);
    o1.w = fmaxf(acc[i][7] * sc, 0.f);
    if (MODE == 0) {
      size_t base = ((size_t)(tc >> 1) * (N + 1) + gr) * 16 + (tc & 1) * 8;
      *(float4*)&Out[base] = o0;
      *(float4*)&Out[base + 4] = o1;
    } else {
      *(float4*)&Out[(size_t)gr * 128 + c0] = o0;
      *(float4*)&Out[(size_t)gr * 128 + c0 + 4] = o1;
    }
  }
}

// ------------- batched head: pool + lin1 + ReLU + lin2 (blockIdx.y = class) -------------
__device__ __forceinline__ int lowerb(const int* __restrict__ a, int n, int v) {
  int lo = 0, hi = n;
  while (lo < hi) {
    int m = (lo + hi) >> 1;
    if (a[m] < v) lo = m + 1; else hi = m;
  }
  return lo;
}

__global__ __launch_bounds__(128) void k_head(const float* __restrict__ Hall, long hstride,
                                              const int* __restrict__ batch, int N,
                                              const float* __restrict__ l1w,
                                              const float* __restrict__ l1b,
                                              const float* __restrict__ l2w,
                                              const float* __restrict__ l2b,
                                              float* __restrict__ out, int G) {
  const int g = blockIdx.x;
  const int c = blockIdx.y;
  const int t = threadIdx.x;
  const float* __restrict__ h = Hall + (size_t)c * hstride;
  const float* __restrict__ w1 = l1w + (size_t)c * D * D;
  const float* __restrict__ w2 = l2w + (size_t)c * D;
  int lo = lowerb(batch, N, g);
  int hi = lowerb(batch, N, g + 1);
  float p = 0.f;
  for (int i = lo; i < hi; ++i) p += h[(size_t)i * 128 + t];
  __shared__ float pl[128];
  pl[t] = p;
  __syncthreads();
  float z = l1b[(size_t)c * D + t];
#pragma unroll 8
  for (int k = 0; k < 128; ++k) z = fmaf(pl[k], w1[k * 128 + t], z);
  z = fmaxf(z, 0.f);
  float o = z * w2[t];
#pragma unroll
  for (int off = 32; off > 0; off >>= 1) o += __shfl_xor(o, off, 64);
  __shared__ float s2[2];
  if ((t & 63) == 0) s2[t >> 6] = o;
  __syncthreads();
  if (t == 0) out[(size_t)g * CLS + c] = s2[0] + s2[1] + l2b[c];
}

extern "C" void kernel_launch(void* const* d_in, const int* in_sizes, int n_in,
                              void* d_out, int out_size, void* d_ws, size_t ws_size,
                              hipStream_t stream) {
  const float* x = (const float*)d_in[0];
  const int* eidx = (const int*)d_in[1];
  const int* batch = (const int*)d_in[2];
  const float* conv_w = (const float*)d_in[3];
  const float* conv_b = (const float*)d_in[4];
  const float* lin1_w = (const float*)d_in[5];
  const float* lin1_b = (const float*)d_in[6];
  const float* lin2_w = (const float*)d_in[7];
  const float* lin2_b = (const float*)d_in[8];
  float* out = (float*)d_out;

  const int N = in_sizes[0] / D;
  const int E = in_sizes[1] / 2;
  const int G = out_size / CLS;
  const int* row = eidx;
  const int* col = eidx + E;

  int bshift = 10;
  while ((1 << bshift) < E / NBKT + 32768) ++bshift;
  const long TS = (long)(N + 1) * 128;  // per-class slice-table stride (floats)
  const long ZS = (long)N * 128;        // per-class row-major stride (floats)

  char* ws = (char*)d_ws;
  size_t off = 0;
  auto alloc = [&](size_t bytes) -> void* {
    void* p = ws + off;
    off += (bytes + 255) & ~(size_t)255;
    return p;
  };
  float* Zall = (float*)alloc((size_t)CLS * ZS * 4);
  float* Tall = (float*)alloc((size_t)CLS * TS * 4);
  unsigned short* srcs = (unsigned short*)alloc(((size_t)E + 16 * (size_t)N + 64) * 2);
  int* cnt    = (int*)alloc(((size_t)N * 2 + NBKT) * 4);
  int* fillc  = cnt + N;
  int* bfill  = cnt + 2 * N;
  int* rptr2  = (int*)alloc((size_t)(N + 1) * 4);
  float* dinv = (float*)alloc((size_t)N * 4);
  unsigned* pairs = (unsigned*)Tall;  // alias: dead before k_zsent/k_scale
  (void)ws_size; (void)n_in;

  hipMemsetAsync(cnt, 0, ((size_t)N * 2 + NBKT) * 4, stream);
  const int eb = (E + 255) / 256;
  const int nb = (N + 255) / 256;
  k_count<<<eb, 256, 0, stream>>>(col, cnt, E);
  k_exscan<<<1, 1024, 0, stream>>>(cnt, rptr2, N);
  k_prep<<<nb, 256, 0, stream>>>(cnt, rptr2, dinv, srcs, N);
  k_bin<<<1024, 256, 0, stream>>>(row, col, bfill, pairs, E, (float)NBKT / (float)N, bshift);
  k_fill2<<<1024, 256, 0, stream>>>(pairs, bfill, rptr2, fillc, srcs, bshift);
  k_zsent<<<2, 256, 0, stream>>>(Tall, N);

  const int NB64 = (N + 63) / 64;
  const int gb = (N + 127) / 128;
  float* Z0 = Zall;

  // shared layer 0
  k_scale<<<dim3(NB64, 8), 256, 0, stream>>>(x, dinv, Tall, N);
  k_gather<<<NB64 * 8, 256, 0, stream>>>(Tall, rptr2, srcs, dinv, Z0, N);

  // layer 1 (A shared across classes)
  k_gemm3<0><<<dim3(gb, CLS), 256, 0, stream>>>(Z0, 0L, conv_w + 0 * D * D,
                                                conv_b + 0 * D, dinv, Tall, TS, N);
  for (int c = 0; c < CLS; ++c)
    k_gather<<<NB64 * 8, 256, 0, stream>>>(Tall + c * TS, rptr2, srcs, dinv, Zall + c * ZS, N);

  // layer 2
  k_gemm3<0><<<dim3(gb, CLS), 256, 0, stream>>>(Zall, ZS, conv_w + 1 * D * D,
                                                conv_b + 1 * D, dinv, Tall, TS, N);
  for (int c = 0; c < CLS; ++c)
    k_gather<<<NB64 * 8, 256, 0, stream>>>(Tall + c * TS, rptr2, srcs, dinv, Zall + c * ZS, N);

  // layer 3 -> H (row-major, stored in the table slots)
  k_gemm3<1><<<dim3(gb, CLS), 256, 0, stream>>>(Zall, ZS, conv_w + 2 * D * D,
                                                conv_b + 2 * D, dinv, Tall, TS, N);

  // heads
  k_head<<<dim3(G, CLS), 128, 0, stream>>>(Tall, TS, batch, N,
                                           lin1_w, lin1_b, lin2_w, lin2_b, out, G);
}

// Round 9
// 939.228 us; speedup vs baseline: 1.1780x; 1.1780x over previous
//
#include <hip/hip_runtime.h>

#define D 128
#define CLS 3
#define LAY 3
#define NBKT 8

// ---------------- CSR build ----------------
__global__ void k_count(const int* __restrict__ col, int* __restrict__ cnt, int E) {
  int e = blockIdx.x * blockDim.x + threadIdx.x;
  if (e < E) atomicAdd(&cnt[col[e]], 1);
}

// exclusive scan of PADDED counts: pad(cnt) = (cnt+15)&~15  -> rptr2
__global__ __launch_bounds__(1024) void k_exscan(const int* __restrict__ cnt,
                                                 int* __restrict__ ptr, int n) {
  __shared__ int wsum[16];
  __shared__ int s_carry;
  const int tid = threadIdx.x;
  const int lane = tid & 63, wid = tid >> 6;
  if (tid == 0) s_carry = 0;
  __syncthreads();
  for (int base = 0; base < n; base += 1024) {
    int i = base + tid;
    int v = (i < n) ? ((cnt[i] + 15) & ~15) : 0;
    int s = v;
#pragma unroll
    for (int off = 1; off < 64; off <<= 1) {
      int t = __shfl_up(s, off, 64);
      if (lane >= off) s += t;
    }
    if (lane == 63) wsum[wid] = s;
    __syncthreads();
    if (wid == 0 && lane < 16) {
      int ws = wsum[lane];
#pragma unroll
      for (int off = 1; off < 16; off <<= 1) {
        int t = __shfl_up(ws, off, 16);
        if (lane >= off) ws += t;
      }
      wsum[lane] = ws;
    }
    __syncthreads();
    int carry = s_carry;
    int woff = wid ? wsum[wid - 1] : 0;
    if (i < n) ptr[i] = carry + woff + (s - v);
    __syncthreads();
    if (tid == 1023) s_carry = carry + wsum[15];
    __syncthreads();
  }
  if (tid == 0) ptr[n] = s_carry;
}

// dinv + fill CSR padding slots with sentinel N
__global__ void k_prep(const int* __restrict__ cnt, const int* __restrict__ rptr2,
                       float* __restrict__ dinv, unsigned short* __restrict__ srcs, int N) {
  int i = blockIdx.x * blockDim.x + threadIdx.x;
  if (i < N) {
    dinv[i] = rsqrtf((float)(cnt[i] + 1));
    int e = rptr2[i] + cnt[i], e1 = rptr2[i + 1];
    for (; e < e1; ++e) srcs[e] = (unsigned short)N;  // sentinel -> zero row
  }
}

// phase A: bin edges into 8 even col-range buckets (fixed-stride pairs layout)
__global__ __launch_bounds__(256) void k_bin(const int* __restrict__ row,
                                             const int* __restrict__ col,
                                             int* __restrict__ bfill,
                                             unsigned* __restrict__ pairs,
                                             int E, float bscale, int bshift) {
  __shared__ int lh[NBKT], gbase[NBKT], lcur[NBKT];
  const int tid = threadIdx.x;
  const int chunk = (E + gridDim.x - 1) / gridDim.x;
  const int s0 = blockIdx.x * chunk;
  const int s1 = min(s0 + chunk, E);
  if (tid < NBKT) lh[tid] = 0;
  __syncthreads();
  for (int e = s0 + tid; e < s1; e += 256) {
    int b = min(NBKT - 1, (int)((float)col[e] * bscale));
    atomicAdd(&lh[b], 1);
  }
  __syncthreads();
  if (tid < NBKT) {
    gbase[tid] = atomicAdd(&bfill[tid], lh[tid]);
    lcur[tid] = 0;
  }
  __syncthreads();
  for (int e = s0 + tid; e < s1; e += 256) {
    int c = col[e], r = row[e];
    int b = min(NBKT - 1, (int)((float)c * bscale));
    int off = atomicAdd(&lcur[b], 1);
    pairs[(b << bshift) + gbase[b] + off] = ((unsigned)r << 16) | (unsigned)c;
  }
}

// phase B: XCD-affine scatter into padded CSR (bucket b only on blocks with blockIdx&7==b)
__global__ __launch_bounds__(256) void k_fill2(const unsigned* __restrict__ pairs,
                                               const int* __restrict__ bfill,
                                               const int* __restrict__ rptr2,
                                               int* __restrict__ fillc,
                                               unsigned short* __restrict__ srcs,
                                               int bshift) {
  const int b = blockIdx.x & 7;
  const int bi = blockIdx.x >> 3;
  const int cap = bfill[b];
  const int stride = (gridDim.x >> 3) * blockDim.x;
  const unsigned* __restrict__ bp = pairs + ((size_t)b << bshift);
  for (int idx = bi * blockDim.x + threadIdx.x; idx < cap; idx += stride) {
    unsigned p = bp[idx];
    int c = (int)(p & 0xFFFFu);
    int pos = rptr2[c] + atomicAdd(&fillc[c], 1);
    srcs[pos] = (unsigned short)(p >> 16);
  }
}

// zero the 8 sentinel rows of each of the 3 slice tables
__global__ void k_zsent(float* __restrict__ Tall, int N) {
  int t = blockIdx.x * blockDim.x + threadIdx.x;   // 3*8*16 = 384
  if (t < CLS * 8 * 16) {
    int c = t / 128, rem = t % 128;
    int s = rem / 16, f = rem % 16;
    Tall[((size_t)c * 8 + s) * (size_t)(N + 1) * 16 + (size_t)N * 16 + f] = 0.f;
  }
}

// ---- T0 = x * dinv, slice-major [8][N+1][16] ----
__global__ __launch_bounds__(256) void k_scale(const float* __restrict__ x,
                                               const float* __restrict__ dinv,
                                               float* __restrict__ T, int N) {
  const int s = blockIdx.y;
  const int i = blockIdx.x * 64 + (threadIdx.x >> 2);
  const int f = threadIdx.x & 3;
  if (i < N) {
    float4 v = *(const float4*)&x[(size_t)i * 128 + s * 16 + f * 4];
    float d = dinv[i];
    v.x *= d; v.y *= d; v.z *= d; v.w *= d;
    *(float4*)&T[((size_t)s * (N + 1) + i) * 16 + f * 4] = v;
  }
}

// ---- XCD-sliced gather: Z[i] = dinv[i]*(T[i] + sum T[srcs])  (padded CSR, u16 srcs) ----
__global__ __launch_bounds__(256, 4) void k_gather(const float* __restrict__ T,
                                                   const int* __restrict__ rptr2,
                                                   const unsigned short* __restrict__ srcs,
                                                   const float* __restrict__ dinv,
                                                   float* __restrict__ Z, int N) {
  const int s = blockIdx.x & 7;
  const int chunk = blockIdx.x >> 3;
  const int i = chunk * 64 + (threadIdx.x >> 2);
  const int f = threadIdx.x & 3;
  if (i >= N) return;
  const float4* __restrict__ Ts = (const float4*)(T + (size_t)s * (N + 1) * 16);
  const int e0 = rptr2[i], e1 = rptr2[i + 1];
  float4 a0 = Ts[(size_t)i * 4 + f];  // self term
  float4 a1 = make_float4(0.f, 0.f, 0.f, 0.f);
  float4 a2 = make_float4(0.f, 0.f, 0.f, 0.f);
  float4 a3 = make_float4(0.f, 0.f, 0.f, 0.f);
  ushort4 q = make_ushort4(0, 0, 0, 0);
  if (e0 < e1) q = *(const ushort4*)(srcs + e0 + (f << 2));
  for (int eb = e0; eb < e1; eb += 16) {
    ushort4 qn = q;
    if (eb + 16 < e1) qn = *(const ushort4*)(srcs + eb + 16 + (f << 2));
    const int qx = q.x, qy = q.y, qz = q.z, qw = q.w;
    float4 v[16];
#pragma unroll
    for (int k = 0; k < 16; ++k) {
      const int comp = k & 3;
      const int val = comp == 0 ? qx : comp == 1 ? qy : comp == 2 ? qz : qw;
      const int j = __shfl(val, k >> 2, 4);
      v[k] = Ts[(size_t)j * 4 + f];
    }
#pragma unroll
    for (int k = 0; k < 16; k += 4) {
      a0.x += v[k].x;     a0.y += v[k].y;     a0.z += v[k].z;     a0.w += v[k].w;
      a1.x += v[k + 1].x; a1.y += v[k + 1].y; a1.z += v[k + 1].z; a1.w += v[k + 1].w;
      a2.x += v[k + 2].x; a2.y += v[k + 2].y; a2.z += v[k + 2].z; a2.w += v[k + 2].w;
      a3.x += v[k + 3].x; a3.y += v[k + 3].y; a3.z += v[k + 3].z; a3.w += v[k + 3].w;
    }
    q = qn;
  }
  const float d = dinv[i];
  float4 r;
  r.x = (a0.x + a1.x + a2.x + a3.x) * d;
  r.y = (a0.y + a1.y + a2.y + a3.y) * d;
  r.z = (a0.z + a1.z + a2.z + a3.z) * d;
  r.w = (a0.w + a1.w + a2.w + a3.w) * d;
  *(float4*)&Z[(size_t)i * 128 + s * 16 + f * 4] = r;
}

// ---- batched 3-class GEMM + bias + L2-norm + ReLU (+dinv, slice-major) ----
// 128x128 tile, BK=16, 8x8 micro-tile with rows split 4+4 at distance 64:
// A-fragment ds_read_b128s are 16B-contiguous across the 16 tr lanes (2-way, free).
// red[] aliased over As/Ws -> 16.4 KB LDS. Simple in-loop staging (no prefetch branch).
template <int MODE>
__global__ __launch_bounds__(256, 4) void k_gemm3(const float* __restrict__ Abase, long astride,
                                                  const float* __restrict__ Wl,
                                                  const float* __restrict__ bl,
                                                  const float* __restrict__ dinv,
                                                  float* __restrict__ Obase, long ostride,
                                                  int N) {
  __shared__ __align__(16) char smem_raw[16 * 128 * 4 * 2];  // 16 KB
  float* __restrict__ Asf = (float*)smem_raw;                // [16][128]
  float* __restrict__ Wsf = (float*)(smem_raw + 8192);       // [16][128]
  typedef float redrow[17];
  redrow* red = (redrow*)smem_raw;                           // [128][17], epilogue only

  const int c = blockIdx.y;
  const float* __restrict__ A = Abase + (size_t)c * astride;
  const float* __restrict__ W = Wl + (size_t)c * (LAY * D * D);
  const float* __restrict__ bias = bl + (size_t)c * (LAY * D);
  float* __restrict__ Out = Obase + (size_t)c * ostride;

  const int tid = threadIdx.x;
  const int tr = tid & 15;
  const int tc = tid >> 4;
  const int m0 = blockIdx.x * 128;
  float acc[8][8];
#pragma unroll
  for (int i = 0; i < 8; ++i)
#pragma unroll
    for (int j = 0; j < 8; ++j) acc[i][j] = 0.f;

  const int lr = tid >> 1;       // 0..127 A row in tile
  const int lq = tid & 1;        // k half
  const int gr_l = m0 + lr;

  for (int kc = 0; kc < 128; kc += 16) {
    float4 va0 = make_float4(0.f, 0.f, 0.f, 0.f), va1 = va0;
    if (gr_l < N) {
      va0 = *(const float4*)&A[(size_t)gr_l * 128 + kc + lq * 8];
      va1 = *(const float4*)&A[(size_t)gr_l * 128 + kc + lq * 8 + 4];
    }
    Asf[(lq * 8 + 0) * 128 + lr] = va0.x;
    Asf[(lq * 8 + 1) * 128 + lr] = va0.y;
    Asf[(lq * 8 + 2) * 128 + lr] = va0.z;
    Asf[(lq * 8 + 3) * 128 + lr] = va0.w;
    Asf[(lq * 8 + 4) * 128 + lr] = va1.x;
    Asf[(lq * 8 + 5) * 128 + lr] = va1.y;
    Asf[(lq * 8 + 6) * 128 + lr] = va1.z;
    Asf[(lq * 8 + 7) * 128 + lr] = va1.w;
#pragma unroll
    for (int it = 0; it < 2; ++it) {
      const int lin = tid + it * 256;
      const int kr = lin >> 5;
      const int cq = lin & 31;
      *(float4*)&Wsf[kr * 128 + cq * 4] = *(const float4*)&W[(size_t)(kc + kr) * 128 + cq * 4];
    }
    __syncthreads();
#pragma unroll
    for (int kk = 0; kk < 16; ++kk) {
      float4 a4 = *(const float4*)&Asf[kk * 128 + tr * 4];
      float4 a4b = *(const float4*)&Asf[kk * 128 + 64 + tr * 4];
      float4 b4 = *(const float4*)&Wsf[kk * 128 + tc * 8];
      float4 b4b = *(const float4*)&Wsf[kk * 128 + tc * 8 + 4];
      float a[8] = {a4.x, a4.y, a4.z, a4.w, a4b.x, a4b.y, a4b.z, a4b.w};
      float b[8] = {b4.x, b4.y, b4.z, b4.w, b4b.x, b4b.y, b4b.z, b4b.w};
#pragma unroll
      for (int i = 0; i < 8; ++i)
#pragma unroll
        for (int j = 0; j < 8; ++j) acc[i][j] = fmaf(a[i], b[j], acc[i][j]);
    }
    __syncthreads();
  }

  // epilogue: bias, row L2-norm, relu, (dinv), store. rows: tr*4+i and 64+tr*4+(i-4).
  const int c0 = tc * 8;
  float bj[8];
#pragma unroll
  for (int j = 0; j < 8; ++j) bj[j] = bias[c0 + j];
#pragma unroll
  for (int i = 0; i < 8; ++i) {
    const int r = (i < 4) ? (tr * 4 + i) : (64 + tr * 4 + i - 4);
    float rs = 0.f;
#pragma unroll
    for (int j = 0; j < 8; ++j) {
      acc[i][j] += bj[j];
      rs = fmaf(acc[i][j], acc[i][j], rs);
    }
    red[r][tc] = rs;
  }
  __syncthreads();
#pragma unroll
  for (int i = 0; i < 8; ++i) {
    const int r = (i < 4) ? (tr * 4 + i) : (64 + tr * 4 + i - 4);
    const int gr = m0 + r;
    if (gr >= N) continue;
    float rsum = 0.f;
#pragma unroll
    for (int q = 0; q < 16; ++q) rsum += red[r][q];
    float sc = 1.0f / fmaxf(sqrtf(rsum), 1e-12f);
    if (MODE == 0) sc *= dinv[gr];
    float4 o0, o1;
    o0.x = fmaxf(acc[i][0] * sc, 0.f);
    o0.y = fmaxf(acc[i][1] * sc, 0.f);
    o0.z = fmaxf(acc[i][2] * sc, 0.f);
    o0.w = fmaxf(acc[i][3] * sc, 0.f);
    o1.x = fmaxf(acc[i][4] * sc, 0.f);
    o1.y = fmaxf(acc[i][5] * sc, 0.f);
    o1.z = fmaxf(acc[i][6] * sc, 0.f);
    o1.w = fmaxf(acc[i][7] * sc, 0.f);
    if (MODE == 0) {
      size_t base = ((size_t)(tc >> 1) * (N + 1) + gr) * 16 + (tc & 1) * 8;
      *(float4*)&Out[base] = o0;
      *(float4*)&Out[base + 4] = o1;
    } else {
      *(float4*)&Out[(size_t)gr * 128 + c0] = o0;
      *(float4*)&Out[(size_t)gr * 128 + c0 + 4] = o1;
    }
  }
}

// ------------- batched head: pool + lin1 + ReLU + lin2 (blockIdx.y = class) -------------
__device__ __forceinline__ int lowerb(const int* __restrict__ a, int n, int v) {
  int lo = 0, hi = n;
  while (lo < hi) {
    int m = (lo + hi) >> 1;
    if (a[m] < v) lo = m + 1; else hi = m;
  }
  return lo;
}

__global__ __launch_bounds__(128) void k_head(const float* __restrict__ Hall, long hstride,
                                              const int* __restrict__ batch, int N,
                                              const float* __restrict__ l1w,
                                              const float* __restrict__ l1b,
                                              const float* __restrict__ l2w,
                                              const float* __restrict__ l2b,
                                              float* __restrict__ out, int G) {
  const int g = blockIdx.x;
  const int c = blockIdx.y;
  const int t = threadIdx.x;
  const float* __restrict__ h = Hall + (size_t)c * hstride;
  const float* __restrict__ w1 = l1w + (size_t)c * D * D;
  const float* __restrict__ w2 = l2w + (size_t)c * D;
  int lo = lowerb(batch, N, g);
  int hi = lowerb(batch, N, g + 1);
  float p = 0.f;
  for (int i = lo; i < hi; ++i) p += h[(size_t)i * 128 + t];
  __shared__ float pl[128];
  pl[t] = p;
  __syncthreads();
  float z = l1b[(size_t)c * D + t];
#pragma unroll 8
  for (int k = 0; k < 128; ++k) z = fmaf(pl[k], w1[k * 128 + t], z);
  z = fmaxf(z, 0.f);
  float o = z * w2[t];
#pragma unroll
  for (int off = 32; off > 0; off >>= 1) o += __shfl_xor(o, off, 64);
  __shared__ float s2[2];
  if ((t & 63) == 0) s2[t >> 6] = o;
  __syncthreads();
  if (t == 0) out[(size_t)g * CLS + c] = s2[0] + s2[1] + l2b[c];
}

extern "C" void kernel_launch(void* const* d_in, const int* in_sizes, int n_in,
                              void* d_out, int out_size, void* d_ws, size_t ws_size,
                              hipStream_t stream) {
  const float* x = (const float*)d_in[0];
  const int* eidx = (const int*)d_in[1];
  const int* batch = (const int*)d_in[2];
  const float* conv_w = (const float*)d_in[3];
  const float* conv_b = (const float*)d_in[4];
  const float* lin1_w = (const float*)d_in[5];
  const float* lin1_b = (const float*)d_in[6];
  const float* lin2_w = (const float*)d_in[7];
  const float* lin2_b = (const float*)d_in[8];
  float* out = (float*)d_out;

  const int N = in_sizes[0] / D;
  const int E = in_sizes[1] / 2;
  const int G = out_size / CLS;
  const int* row = eidx;
  const int* col = eidx + E;

  int bshift = 10;
  while ((1 << bshift) < E / NBKT + 32768) ++bshift;
  const long TS = (long)(N + 1) * 128;  // per-class slice-table stride (floats)
  const long ZS = (long)N * 128;        // per-class row-major stride (floats)

  char* ws = (char*)d_ws;
  size_t off = 0;
  auto alloc = [&](size_t bytes) -> void* {
    void* p = ws + off;
    off += (bytes + 255) & ~(size_t)255;
    return p;
  };
  float* Zall = (float*)alloc((size_t)CLS * ZS * 4);
  float* Tall = (float*)alloc((size_t)CLS * TS * 4);
  unsigned short* srcs = (unsigned short*)alloc(((size_t)E + 16 * (size_t)N + 64) * 2);
  int* cnt    = (int*)alloc(((size_t)N * 2 + NBKT) * 4);
  int* fillc  = cnt + N;
  int* bfill  = cnt + 2 * N;
  int* rptr2  = (int*)alloc((size_t)(N + 1) * 4);
  float* dinv = (float*)alloc((size_t)N * 4);
  unsigned* pairs = (unsigned*)Tall;  // alias: dead before k_zsent/k_scale
  (void)ws_size; (void)n_in;

  hipMemsetAsync(cnt, 0, ((size_t)N * 2 + NBKT) * 4, stream);
  const int eb = (E + 255) / 256;
  const int nb = (N + 255) / 256;
  k_count<<<eb, 256, 0, stream>>>(col, cnt, E);
  k_exscan<<<1, 1024, 0, stream>>>(cnt, rptr2, N);
  k_prep<<<nb, 256, 0, stream>>>(cnt, rptr2, dinv, srcs, N);
  k_bin<<<1024, 256, 0, stream>>>(row, col, bfill, pairs, E, (float)NBKT / (float)N, bshift);
  k_fill2<<<1024, 256, 0, stream>>>(pairs, bfill, rptr2, fillc, srcs, bshift);
  k_zsent<<<2, 256, 0, stream>>>(Tall, N);

  const int NB64 = (N + 63) / 64;
  const int gb = (N + 127) / 128;
  float* Z0 = Zall;

  // shared layer 0
  k_scale<<<dim3(NB64, 8), 256, 0, stream>>>(x, dinv, Tall, N);
  k_gather<<<NB64 * 8, 256, 0, stream>>>(Tall, rptr2, srcs, dinv, Z0, N);

  // layer 1 (A shared across classes)
  k_gemm3<0><<<dim3(gb, CLS), 256, 0, stream>>>(Z0, 0L, conv_w + 0 * D * D,
                                                conv_b + 0 * D, dinv, Tall, TS, N);
  for (int c = 0; c < CLS; ++c)
    k_gather<<<NB64 * 8, 256, 0, stream>>>(Tall + c * TS, rptr2, srcs, dinv, Zall + c * ZS, N);

  // layer 2
  k_gemm3<0><<<dim3(gb, CLS), 256, 0, stream>>>(Zall, ZS, conv_w + 1 * D * D,
                                                conv_b + 1 * D, dinv, Tall, TS, N);
  for (int c = 0; c < CLS; ++c)
    k_gather<<<NB64 * 8, 256, 0, stream>>>(Tall + c * TS, rptr2, srcs, dinv, Zall + c * ZS, N);

  // layer 3 -> H (row-major, stored in the table slots)
  k_gemm3<1><<<dim3(gb, CLS), 256, 0, stream>>>(Zall, ZS, conv_w + 2 * D * D,
                                                conv_b + 2 * D, dinv, Tall, TS, N);

  // heads
  k_head<<<dim3(G, CLS), 128, 0, stream>>>(Tall, TS, batch, N,
                                           lin1_w, lin1_b, lin2_w, lin2_b, out, G);
}